// Round 1
// baseline (59.683 us; speedup 1.0000x reference)
//
#include <hip/hip_runtime.h>

#define MV 16
#define TABLE_ELEMS (MV * MV * MV)   // 4096 floats = 16 KiB

// Transpose gp[i][j][k] -> gpt[j][k][i] so the hot kernel's inner i-loop reads
// 16 consecutive floats (one s_load_dwordx16 per (j,k), 64B aligned).
__global__ void gp_transpose_kernel(const float* __restrict__ gp,
                                    float* __restrict__ gpt) {
    int t = blockIdx.x * blockDim.x + threadIdx.x;
    if (t < TABLE_ELEMS) {
        int i  = t >> 8;        // gp index: i*256 + j*16 + k
        int jk = t & 255;
        gpt[jk * MV + i] = gp[t];
    }
}

// TRANSPOSED=true : g points to gpt[j][k][i] (preferred, wide scalar loads)
// TRANSPOSED=false: g points to gp[i][j][k]  (fallback, per-dword scalar loads)
template <bool TRANSPOSED>
__global__ __launch_bounds__(256) void gp_main_kernel(
    const float* __restrict__ g,
    const float* __restrict__ x,
    const float* __restrict__ y,
    float* __restrict__ out,
    int npix)
{
    int idx = blockIdx.x * blockDim.x + threadIdx.x;
    if (idx >= npix) return;

    const float4* __restrict__ xv =
        reinterpret_cast<const float4*>(x) + (size_t)idx * 4;
    const float4* __restrict__ yv =
        reinterpret_cast<const float4*>(y) + (size_t)idx * 4;

    float xr[MV], yr[MV], acc[MV];
    #pragma unroll
    for (int q = 0; q < 4; ++q) {
        float4 t = xv[q];
        xr[4 * q + 0] = t.x; xr[4 * q + 1] = t.y;
        xr[4 * q + 2] = t.z; xr[4 * q + 3] = t.w;
        float4 u = yv[q];
        yr[4 * q + 0] = u.x; yr[4 * q + 1] = u.y;
        yr[4 * q + 2] = u.z; yr[4 * q + 3] = u.w;
    }
    #pragma unroll
    for (int i = 0; i < MV; ++i) acc[i] = 0.0f;

    // out[i] += gp[i,j,k] * (x[j]*y[k]); gp address is wave-uniform -> s_load,
    // costs no VALU slots. 256 muls + 4096 FMAs per thread.
    #pragma unroll
    for (int j = 0; j < MV; ++j) {
        #pragma unroll
        for (int k = 0; k < MV; ++k) {
            float p = xr[j] * yr[k];
            #pragma unroll
            for (int i = 0; i < MV; ++i) {
                float gv = TRANSPOSED ? g[(j * MV + k) * MV + i]
                                      : g[(i * MV + j) * MV + k];
                acc[i] = fmaf(gv, p, acc[i]);
            }
        }
    }

    float4* __restrict__ ov = reinterpret_cast<float4*>(out) + (size_t)idx * 4;
    #pragma unroll
    for (int q = 0; q < 4; ++q) {
        ov[q] = make_float4(acc[4 * q + 0], acc[4 * q + 1],
                            acc[4 * q + 2], acc[4 * q + 3]);
    }
}

extern "C" void kernel_launch(void* const* d_in, const int* in_sizes, int n_in,
                              void* d_out, int out_size, void* d_ws, size_t ws_size,
                              hipStream_t stream) {
    const float* gp = (const float*)d_in[0];   // [16,16,16]
    const float* x  = (const float*)d_in[1];   // [2048,256,16]
    const float* y  = (const float*)d_in[2];   // [2048,256,16]
    float* out      = (float*)d_out;           // [2048,256,16]

    int npix = in_sizes[1] / MV;               // 524288
    int blocks = (npix + 255) / 256;

    if (ws_size >= TABLE_ELEMS * sizeof(float)) {
        float* gpt = (float*)d_ws;
        gp_transpose_kernel<<<16, 256, 0, stream>>>(gp, gpt);
        gp_main_kernel<true><<<blocks, 256, 0, stream>>>(gpt, x, y, out, npix);
    } else {
        gp_main_kernel<false><<<blocks, 256, 0, stream>>>(gp, x, y, out, npix);
    }
}

// Round 2
// 27.897 us; speedup vs baseline: 2.1394x; 2.1394x over previous
//
#include <hip/hip_runtime.h>

#define MV 16
#define TPW 4   // 16-pixel tiles per wave

typedef __attribute__((ext_vector_type(8))) short short8;
typedef __attribute__((ext_vector_type(4))) float f32x4;

// ---------------------------------------------------------------------------
// Pack gp[i][j][k] (fp32) into the per-lane B-fragment layout for
// mfma_f32_16x16x32_bf16, bf16 bits:
//   gpbf[(c*64 + lane)*8 + e] = bf16( gp[i][j][k] )
//   where i = lane&15 (B col), jk = 32c + 8*(lane>>4) + e, j = jk>>4, k = jk&15.
// Main kernel then loads frag_b[c] as one coalesced 16B load per lane.
// ---------------------------------------------------------------------------
__global__ void gp_pack_kernel(const float* __restrict__ gp,
                               unsigned short* __restrict__ gpbf) {
    int t = blockIdx.x * blockDim.x + threadIdx.x;
    if (t < 4096) {
        int e    = t & 7;
        int lane = (t >> 3) & 63;
        int c    = t >> 9;
        int i  = lane & 15;
        int jk = 32 * c + 8 * (lane >> 4) + e;
        int j = jk >> 4, k = jk & 15;
        __bf16 h = (__bf16)gp[(i * MV + j) * MV + k];
        gpbf[t] = __builtin_bit_cast(unsigned short, h);
    }
}

// ---------------------------------------------------------------------------
// out[p,i] = sum_{jk} gp2[jk,i] * (x[p,j]*y[p,k])  as MFMA:
//   per wave, per 16-pixel tile: D[16pix x 16i] = sum_{c=0..7} A_c[16x32] B_c[32x16]
// A-fragment (lane l, chunk c): row p = l&15, k-slice = 8*(l>>4)+e:
//   j = 2c + (l>>5)  (fixed parity per lane),  y-index = 8*((l>>4)&1) + e (fixed).
// So per lane: y-slice loaded once per tile, x parity selected per chunk.
// ---------------------------------------------------------------------------
__global__ __launch_bounds__(256) void gp_mfma_kernel(
    const unsigned short* __restrict__ gpbf,
    const float* __restrict__ x,
    const float* __restrict__ y,
    float* __restrict__ out,
    int ntiles)
{
    const int lane = threadIdx.x & 63;
    const int wid  = threadIdx.x >> 6;
    const int tile0 = (blockIdx.x * 4 + wid) * TPW;

    // B fragments: resident for the whole kernel (32 VGPRs)
    short8 bfrag[8];
    #pragma unroll
    for (int c = 0; c < 8; ++c)
        bfrag[c] = *reinterpret_cast<const short8*>(gpbf + (size_t)(c * 64 + lane) * 8);

    const int g    = lane >> 4;        // k-group 0..3
    const int p    = lane & 15;        // pixel-in-tile (A row) == output col i for D
    const int kb   = (g & 1) * 8;      // fixed y k-base for this lane
    const int jpar = g >> 1;           // fixed j parity for this lane

    #pragma unroll
    for (int t = 0; t < TPW; ++t) {
        int tile = tile0 + t;
        if (tile >= ntiles) continue;

        const float* xp = x + ((size_t)tile * 16 + p) * MV;
        const float* yp = y + ((size_t)tile * 16 + p) * MV;

        float4 xv0 = *reinterpret_cast<const float4*>(xp + 0);
        float4 xv1 = *reinterpret_cast<const float4*>(xp + 4);
        float4 xv2 = *reinterpret_cast<const float4*>(xp + 8);
        float4 xv3 = *reinterpret_cast<const float4*>(xp + 12);
        float4 yv0 = *reinterpret_cast<const float4*>(yp + kb);
        float4 yv1 = *reinterpret_cast<const float4*>(yp + kb + 4);

        float ye[8] = {yv0.x, yv0.y, yv0.z, yv0.w, yv1.x, yv1.y, yv1.z, yv1.w};
        float xe[8] = {xv0.x, xv0.z, xv1.x, xv1.z, xv2.x, xv2.z, xv3.x, xv3.z};
        float xo[8] = {xv0.y, xv0.w, xv1.y, xv1.w, xv2.y, xv2.w, xv3.y, xv3.w};

        f32x4 acc = {0.f, 0.f, 0.f, 0.f};
        #pragma unroll
        for (int c = 0; c < 8; ++c) {
            float xj = jpar ? xo[c] : xe[c];   // j = 2c + jpar
            short8 a;
            #pragma unroll
            for (int e = 0; e < 8; ++e) {
                __bf16 h = (__bf16)(xj * ye[e]);   // z[p, jk] in bf16 (RNE)
                a[e] = __builtin_bit_cast(short, h);
            }
            acc = __builtin_amdgcn_mfma_f32_16x16x32_bf16(a, bfrag[c], acc, 0, 0, 0);
        }

        // D: col = lane&15 (=i), row = 4*(lane>>4) + r (=pixel-in-tile)
        float* op = out + ((size_t)tile * 16 + 4 * g) * MV + p;
        op[0 * MV] = acc[0];
        op[1 * MV] = acc[1];
        op[2 * MV] = acc[2];
        op[3 * MV] = acc[3];
    }
}

// ---------------------------------------------------------------------------
// fp32 fallback (round-1 kernel) if workspace is unusable
// ---------------------------------------------------------------------------
__global__ __launch_bounds__(256) void gp_fp32_kernel(
    const float* __restrict__ g,
    const float* __restrict__ x,
    const float* __restrict__ y,
    float* __restrict__ out,
    int npix)
{
    int idx = blockIdx.x * blockDim.x + threadIdx.x;
    if (idx >= npix) return;

    const float4* xv = reinterpret_cast<const float4*>(x) + (size_t)idx * 4;
    const float4* yv = reinterpret_cast<const float4*>(y) + (size_t)idx * 4;

    float xr[MV], yr[MV], acc[MV];
    #pragma unroll
    for (int q = 0; q < 4; ++q) {
        float4 t = xv[q];
        xr[4*q+0] = t.x; xr[4*q+1] = t.y; xr[4*q+2] = t.z; xr[4*q+3] = t.w;
        float4 u = yv[q];
        yr[4*q+0] = u.x; yr[4*q+1] = u.y; yr[4*q+2] = u.z; yr[4*q+3] = u.w;
    }
    #pragma unroll
    for (int i = 0; i < MV; ++i) acc[i] = 0.0f;

    #pragma unroll
    for (int j = 0; j < MV; ++j) {
        #pragma unroll
        for (int k = 0; k < MV; ++k) {
            float pr = xr[j] * yr[k];
            #pragma unroll
            for (int i = 0; i < MV; ++i)
                acc[i] = fmaf(g[(i * MV + j) * MV + k], pr, acc[i]);
        }
    }

    float4* ov = reinterpret_cast<float4*>(out) + (size_t)idx * 4;
    #pragma unroll
    for (int q = 0; q < 4; ++q)
        ov[q] = make_float4(acc[4*q+0], acc[4*q+1], acc[4*q+2], acc[4*q+3]);
}

extern "C" void kernel_launch(void* const* d_in, const int* in_sizes, int n_in,
                              void* d_out, int out_size, void* d_ws, size_t ws_size,
                              hipStream_t stream) {
    const float* gp = (const float*)d_in[0];   // [16,16,16]
    const float* x  = (const float*)d_in[1];   // [npix,16]
    const float* y  = (const float*)d_in[2];   // [npix,16]
    float* out      = (float*)d_out;           // [npix,16]

    int npix = in_sizes[1] / MV;

    if (ws_size >= 4096 * sizeof(unsigned short) && (npix % 16) == 0) {
        unsigned short* gpbf = (unsigned short*)d_ws;
        gp_pack_kernel<<<16, 256, 0, stream>>>(gp, gpbf);
        int ntiles = npix / 16;                       // 32768
        int waves  = (ntiles + TPW - 1) / TPW;        // 8192
        int blocks = (waves + 3) / 4;                 // 2048
        gp_mfma_kernel<<<blocks, 256, 0, stream>>>(gpbf, x, y, out, ntiles);
    } else {
        int blocks = (npix + 255) / 256;
        gp_fp32_kernel<<<blocks, 256, 0, stream>>>(gp, x, y, out, npix);
    }
}